// Round 6
// baseline (59.394 us; speedup 1.0000x reference)
//
#include <hip/hip_runtime.h>
#include <stdint.h>

typedef __bf16 bf16_t;
typedef __attribute__((ext_vector_type(8))) __bf16 bf16x8;
typedef __attribute__((ext_vector_type(4))) __bf16 bf16x4;
typedef __attribute__((ext_vector_type(4))) float f32x4;

#define NB 8
#define NC 256
#define NS 1024
#define NHD 8
#define ND 64
#define NO 512

// 0.125 (1/sqrt(64)) * log2(e), folded into K1 so P = exp2(score)
#define QK_SCALE 0.18033688011112042f

__device__ __forceinline__ f32x4 mfma16(bf16x8 a, bf16x8 b, f32x4 c) {
  return __builtin_amdgcn_mfma_f32_16x16x32_bf16(a, b, c, 0, 0, 0);
}

// async global->LDS, 16B per lane; LDS dest = wave-uniform base + lane*16
__device__ __forceinline__ void gll16(const bf16_t* g, const bf16_t* l) {
  auto gp = (const __attribute__((address_space(1))) void*)(uintptr_t)g;
  auto lp = (__attribute__((address_space(3))) void*)(uint32_t)(uintptr_t)l;
  __builtin_amdgcn_global_load_lds(gp, lp, 16, 0, 0);
}

// ---------------- fused prep: transposes + weight converts ----------------
// z 0..7: in1 batch z -> XT1 ; z 8..15: in2 -> XT2 ; z 16,17: weights
__global__ __launch_bounds__(256) void k_prep(
    const float* __restrict__ in1, const float* __restrict__ in2,
    const float* __restrict__ w0, const float* __restrict__ w1,
    const float* __restrict__ w2, const float* __restrict__ w3,
    bf16_t* __restrict__ xt1, bf16_t* __restrict__ xt2,
    bf16_t* __restrict__ wb0, bf16_t* __restrict__ wb1,
    bf16_t* __restrict__ wb2, bf16_t* __restrict__ wb3) {
  int z = blockIdx.z;
  int tx = threadIdx.x, ty = threadIdx.y;
  if (z < 16) {
    __shared__ float tile[32][33];
    const float* x = (z < 8) ? in1 : in2;
    bf16_t* xt = (z < 8) ? xt1 : xt2;
    int b = z & 7;
    int s0 = blockIdx.x * 32, c0 = blockIdx.y * 32;
    const float* xb = x + (size_t)b * NC * NS;
#pragma unroll
    for (int i = 0; i < 4; ++i)
      tile[ty + 8 * i][tx] = xb[(size_t)(c0 + ty + 8 * i) * NS + s0 + tx];
    __syncthreads();
    bf16_t* xtb = xt + (size_t)b * NS * NC;
#pragma unroll
    for (int i = 0; i < 4; ++i)
      xtb[(size_t)(s0 + ty + 8 * i) * NC + c0 + tx] =
          (bf16_t)tile[tx][ty + 8 * i];
  } else {
    int f = ((blockIdx.y * 32 + blockIdx.x) * 256 + ty * 32 + tx) * 4;
    int mat = f >> 17, off = f & 131071;
    const float* s;
    bf16_t* d;
    if (z == 16) {
      s = mat ? w1 : w0; d = mat ? wb1 : wb0;
    } else {
      s = mat ? w3 : w2; d = mat ? wb3 : wb2;
    }
    float4 v = *reinterpret_cast<const float4*>(s + off);
    bf16x4 o;
    o[0] = (bf16_t)v.x; o[1] = (bf16_t)v.y;
    o[2] = (bf16_t)v.z; o[3] = (bf16_t)v.w;
    *reinterpret_cast<bf16x4*>(d + off) = o;
  }
}

// ---------------- fused projections (K1, K2, VT) ----------------
// grid 768: sel = id>>8 (0:K1 1:K2 2:VT); inner 256: b=id&7, o-blk, s-blk.
// BK=64 chunks, double-buffered global_load_lds, counted vmcnt(8).
// 128x128 tile, 4 waves x 64x64. XOR-swizzle granule(16B) ^= row&7.
__global__ __launch_bounds__(256) void k_proj(
    const bf16_t* __restrict__ Wk1b, const bf16_t* __restrict__ Wk2b,
    const bf16_t* __restrict__ Wv2b, const bf16_t* __restrict__ XT1,
    const bf16_t* __restrict__ XT2, bf16_t* __restrict__ K1,
    bf16_t* __restrict__ K2, bf16_t* __restrict__ VT) {
  __shared__ __align__(16) bf16_t lw[2][128 * 64];
  __shared__ __align__(16) bf16_t lx[2][128 * 64];
  int id = blockIdx.x;
  int sel = id >> 8;
  id &= 255;
  int b = id & 7;
  int ob = ((id >> 3) & 3) * 128;
  int sb = (id >> 5) * 128;
  int tid = threadIdx.x, wid = tid >> 6, lane = tid & 63;
  int lr = lane & 15, g = lane >> 4;
  const bf16_t* W = sel == 0 ? Wk1b : (sel == 1 ? Wk2b : Wv2b);
  const bf16_t* xt = (sel == 0 ? XT1 : XT2) + ((size_t)b * NS + sb) * NC;
  const bf16_t* wsrc = W + (size_t)ob * NC;

  int srow8 = lane >> 3, scol = lane & 7;
  auto stage = [&](int c, int bs) {
#pragma unroll
    for (int i = 0; i < 4; ++i) {
      int row = i * 32 + wid * 8 + srow8;
      int cs = scol ^ (row & 7);
      gll16(wsrc + (size_t)row * NC + c * 64 + cs * 8,
            &lw[bs][(i * 32 + wid * 8) * 64]);
      gll16(xt + (size_t)row * NC + c * 64 + cs * 8,
            &lx[bs][(i * 32 + wid * 8) * 64]);
    }
  };
  stage(0, 0);

  int m0 = (wid >> 1) * 64, n0 = (wid & 1) * 64;
  f32x4 acc[4][4];
#pragma unroll
  for (int mt = 0; mt < 4; ++mt)
#pragma unroll
    for (int nt = 0; nt < 4; ++nt) acc[mt][nt] = (f32x4){0.f, 0.f, 0.f, 0.f};

  for (int c = 0; c < 4; ++c) {
    int cb2 = c & 1;
    if (c < 3) {
      stage(c + 1, cb2 ^ 1);
      asm volatile("s_waitcnt vmcnt(8)" ::: "memory");
    } else {
      asm volatile("s_waitcnt vmcnt(0)" ::: "memory");
    }
    __builtin_amdgcn_s_barrier();
    const bf16_t* aw = sel < 2 ? lw[cb2] : lx[cb2];  // A rows (m)
    const bf16_t* bx = sel < 2 ? lx[cb2] : lw[cb2];  // B rows (n)
#pragma unroll
    for (int kk = 0; kk < 2; ++kk) {
      int j = kk * 4 + g;
      bf16x8 av[4], bv[4];
#pragma unroll
      for (int mt = 0; mt < 4; ++mt) {
        int row = m0 + mt * 16 + lr;
        av[mt] =
            *reinterpret_cast<const bf16x8*>(aw + row * 64 + (j ^ (row & 7)) * 8);
      }
#pragma unroll
      for (int nt = 0; nt < 4; ++nt) {
        int row = n0 + nt * 16 + lr;
        bv[nt] =
            *reinterpret_cast<const bf16x8*>(bx + row * 64 + (j ^ (row & 7)) * 8);
      }
#pragma unroll
      for (int mt = 0; mt < 4; ++mt)
#pragma unroll
        for (int nt = 0; nt < 4; ++nt)
          acc[mt][nt] = mfma16(av[mt], bv[nt], acc[mt][nt]);
    }
    __builtin_amdgcn_s_barrier();
  }

  if (sel < 2) {
    // D rows = o, cols = s; store K[b][h][s][d], d contiguous x4
    float scale = sel == 0 ? QK_SCALE : 1.0f;
    bf16_t* K = sel == 0 ? K1 : K2;
#pragma unroll
    for (int mt = 0; mt < 4; ++mt) {
      int oRow = ob + m0 + mt * 16 + g * 4;
      int hh = oRow >> 6, d0 = oRow & 63;
#pragma unroll
      for (int nt = 0; nt < 4; ++nt) {
        int s = sb + n0 + nt * 16 + lr;
        bf16x4 pk;
        pk[0] = (bf16_t)(acc[mt][nt][0] * scale);
        pk[1] = (bf16_t)(acc[mt][nt][1] * scale);
        pk[2] = (bf16_t)(acc[mt][nt][2] * scale);
        pk[3] = (bf16_t)(acc[mt][nt][3] * scale);
        *reinterpret_cast<bf16x4*>(
            K + (((size_t)b * NHD + hh) * NS + s) * ND + d0) = pk;
      }
    }
  } else {
    // D rows = s, cols = o; store VT[b][h][d][s], s contiguous x4
#pragma unroll
    for (int mt = 0; mt < 4; ++mt) {
      int sRow = sb + m0 + mt * 16 + g * 4;
#pragma unroll
      for (int nt = 0; nt < 4; ++nt) {
        int o = ob + n0 + nt * 16 + lr;
        int hh = o >> 6, d = o & 63;
        bf16x4 pk;
        pk[0] = (bf16_t)acc[mt][nt][0];
        pk[1] = (bf16_t)acc[mt][nt][1];
        pk[2] = (bf16_t)acc[mt][nt][2];
        pk[3] = (bf16_t)acc[mt][nt][3];
        *reinterpret_cast<bf16x4*>(
            VT + (((size_t)b * NHD + hh) * ND + d) * NS + sRow) = pk;
      }
    }
  }
}

// ---------------- fused flash attention (LDS K/V, swapped QK^T) ----------------
// QK^T computed as mfma(K2,K1): lane gets P^T[k=g*4+r][q=lr] -> 4 consecutive
// k per lane -> packed ds_write_b64 into P_lds[q][k] (XOR-swizzled by q&14),
// read back contiguous b128 as PV A-frag. Row-sum l is column-indexed (q=lr),
// reduced across g-groups + redistributed by __shfl in the epilogue.
__global__ __launch_bounds__(256) void k_attn(const bf16_t* __restrict__ K1,
                                              const bf16_t* __restrict__ K2,
                                              const bf16_t* __restrict__ VT,
                                              bf16_t* __restrict__ AO) {
  __shared__ __align__(16) bf16_t kbuf[2][64 * 64];
  __shared__ __align__(16) bf16_t vbuf[2][64 * 64];
  __shared__ __align__(16) bf16_t plds[4][32 * 64];

  int id = blockIdx.x;
  int bh = (id & 7) * 8 + ((id >> 3) & 7);  // id&7 = batch -> per-XCD L2
  int qb = (id >> 6) * 128;
  int tid = threadIdx.x, wid = tid >> 6, lane = tid & 63;
  int lr = lane & 15, g = lane >> 4;
  const bf16_t* k1 = K1 + (size_t)bh * NS * ND;
  const bf16_t* k2 = K2 + (size_t)bh * NS * ND;
  const bf16_t* vt = VT + (size_t)bh * ND * NS;
  int q0 = qb + wid * 32;

  bf16x8 aq[2][2];
#pragma unroll
  for (int qg = 0; qg < 2; ++qg)
#pragma unroll
    for (int kh = 0; kh < 2; ++kh)
      aq[qg][kh] = *reinterpret_cast<const bf16x8*>(
          k1 + (size_t)(q0 + qg * 16 + lr) * ND + kh * 32 + g * 8);

  f32x4 acc[2][4];
  float l[2] = {0.f, 0.f};
#pragma unroll
  for (int qg = 0; qg < 2; ++qg)
#pragma unroll
    for (int dt = 0; dt < 4; ++dt) acc[qg][dt] = (f32x4){0.f, 0.f, 0.f, 0.f};

  int srow = lane >> 3;
  int sx = ((lane & 7) ^ srow) * 8;
  auto stage = [&](int kc, int bs) {
#pragma unroll
    for (int i2 = 0; i2 < 2; ++i2) {
      int row = (wid * 2 + i2) * 8 + srow;
      gll16(k2 + (size_t)(kc + row) * ND + sx, &kbuf[bs][(wid * 2 + i2) * 512]);
      gll16(vt + (size_t)row * NS + kc + sx, &vbuf[bs][(wid * 2 + i2) * 512]);
    }
  };
  stage(0, 0);

  bf16_t* pw = plds[wid];
  int keyr = lr & 14;  // P swizzle key (preserves 16B granule pairs)
  for (int it = 0; it < 16; ++it) {
    int cur = it & 1;
    if (it < 15) {
      stage((it + 1) * 64, cur ^ 1);
      asm volatile("s_waitcnt vmcnt(4)" ::: "memory");
    } else {
      asm volatile("s_waitcnt vmcnt(0)" ::: "memory");
    }
    __builtin_amdgcn_s_barrier();
    const bf16_t* kb = kbuf[cur];
    const bf16_t* vb = vbuf[cur];

    // scores^T = K2 . K1^T : rows = k2-chunk (4 tiles), cols = q (2 tiles)
    f32x4 sct[2][4];
#pragma unroll
    for (int qg = 0; qg < 2; ++qg)
#pragma unroll
      for (int t = 0; t < 4; ++t) sct[qg][t] = (f32x4){0.f, 0.f, 0.f, 0.f};
#pragma unroll
    for (int t = 0; t < 4; ++t) {
      const bf16_t* kr = kb + (t * 16 + lr) * 64;
      bf16x8 b0 = *reinterpret_cast<const bf16x8*>(kr + ((g ^ (lr & 7)) << 3));
      bf16x8 b1 =
          *reinterpret_cast<const bf16x8*>(kr + (((4 + g) ^ (lr & 7)) << 3));
#pragma unroll
      for (int qg = 0; qg < 2; ++qg) {
        sct[qg][t] = mfma16(b0, aq[qg][0], sct[qg][t]);
        sct[qg][t] = mfma16(b1, aq[qg][1], sct[qg][t]);
      }
    }
    // P = exp2; pack 4 consecutive k -> one b64 write per (qg,t)
#pragma unroll
    for (int qg = 0; qg < 2; ++qg)
#pragma unroll
      for (int t = 0; t < 4; ++t) {
        float p0 = __builtin_amdgcn_exp2f(sct[qg][t][0]);
        float p1 = __builtin_amdgcn_exp2f(sct[qg][t][1]);
        float p2 = __builtin_amdgcn_exp2f(sct[qg][t][2]);
        float p3 = __builtin_amdgcn_exp2f(sct[qg][t][3]);
        l[qg] += (p0 + p1) + (p2 + p3);
        bf16x4 pk;
        pk[0] = (bf16_t)p0; pk[1] = (bf16_t)p1;
        pk[2] = (bf16_t)p2; pk[3] = (bf16_t)p3;
        int c8 = (t * 4 + g) ^ keyr;
        *reinterpret_cast<bf16x4*>(pw + (qg * 16 + lr) * 64 + c8 * 4) = pk;
      }
    // PV: A = P (contiguous b128 from swizzled LDS), B = VT chunk
#pragma unroll
    for (int kc2 = 0; kc2 < 2; ++kc2) {
      bf16x8 pA[2];
#pragma unroll
      for (int qg = 0; qg < 2; ++qg)
        pA[qg] = *reinterpret_cast<const bf16x8*>(
            pw + (qg * 16 + lr) * 64 + ((kc2 * 8 + g * 2) ^ keyr) * 4);
#pragma unroll
      for (int dt = 0; dt < 4; ++dt) {
        const bf16_t* vr = vb + (dt * 16 + lr) * 64;
        bf16x8 vB = *reinterpret_cast<const bf16x8*>(
            vr + (((kc2 * 4 + g) ^ (lr & 7)) << 3));
#pragma unroll
        for (int qg = 0; qg < 2; ++qg)
          acc[qg][dt] = mfma16(pA[qg], vB, acc[qg][dt]);
      }
    }
    __builtin_amdgcn_s_barrier();
  }

  // epilogue: reduce l (per q-column) across g-groups, redistribute, store
  int b = bh >> 3, h = bh & 7;
  float L[2];
#pragma unroll
  for (int qg = 0; qg < 2; ++qg) {
    float rs = l[qg];
    rs += __shfl_xor(rs, 16);
    rs += __shfl_xor(rs, 32);
    L[qg] = rs;
  }
#pragma unroll
  for (int qg = 0; qg < 2; ++qg) {
    float linv[4];
#pragma unroll
    for (int r = 0; r < 4; ++r)
      linv[r] = 1.0f / __shfl(L[qg], g * 4 + r);
#pragma unroll
    for (int dt = 0; dt < 4; ++dt) {
      int d = dt * 16 + lr;
#pragma unroll
      for (int r = 0; r < 4; ++r) {
        int s = q0 + qg * 16 + g * 4 + r;
        AO[((size_t)b * NS + s) * NO + h * ND + d] =
            (bf16_t)(acc[qg][dt][r] * linv[r]);
      }
    }
  }
}

// ---------------- output projection, LDS-staged ----------------
__global__ __launch_bounds__(256) void k_oprojs(const bf16_t* __restrict__ Wob,
                                                const bf16_t* __restrict__ AO,
                                                float* __restrict__ OUT) {
  __shared__ __align__(16) bf16_t la[64 * 512];
  __shared__ __align__(16) bf16_t lb[2][128 * 128];
  int id = blockIdx.x;
  int b = id & 7;
  int cb = ((id >> 3) & 3) * 64;
  int sb = (id >> 5) * 128;
  int tid = threadIdx.x, wid = tid >> 6, lane = tid & 63;
  int lr = lane & 15, g = lane >> 4;
  const bf16_t* asrc = Wob + (size_t)cb * NO;
  const bf16_t* bsrc = AO + ((size_t)b * NS + sb) * NO;

  {
    int c = lane;
#pragma unroll
    for (int it = 0; it < 16; ++it) {
      int row = it * 4 + wid;
      int cs = (c & 56) | ((c & 7) ^ (row & 7));
      gll16(asrc + (size_t)row * NO + cs * 8, &la[row * 512]);
    }
  }
  int sr = tid >> 4, sc = tid & 15;
  auto stageB = [&](int ch) {
#pragma unroll
    for (int it = 0; it < 8; ++it) {
      int row = it * 16 + sr;
      int cs = (sc & 8) | ((sc & 7) ^ (row & 7));
      gll16(bsrc + (size_t)row * NO + ch * 128 + cs * 8,
            &lb[ch & 1][(it * 16 + wid * 4) * 128]);
    }
  };
  stageB(0);
  stageB(1);
  asm volatile("s_waitcnt vmcnt(8)" ::: "memory");
  __builtin_amdgcn_s_barrier();

  int c0 = (wid >> 1) * 32, s0 = (wid & 1) * 64;
  f32x4 acc[2][4];
#pragma unroll
  for (int mt = 0; mt < 2; ++mt)
#pragma unroll
    for (int nt = 0; nt < 4; ++nt) acc[mt][nt] = (f32x4){0.f, 0.f, 0.f, 0.f};

#pragma unroll
  for (int ch = 0; ch < 4; ++ch) {
#pragma unroll
    for (int kk = 0; kk < 4; ++kk) {
      int j = kk * 4 + g;
      bf16x8 av[2], bv[4];
#pragma unroll
      for (int mt = 0; mt < 2; ++mt) {
        int row = c0 + mt * 16 + lr;
        int jh = ch * 16 + j;
        int jj = (jh & 56) | ((jh & 7) ^ (row & 7));
        av[mt] = *reinterpret_cast<const bf16x8*>(&la[row * 512 + jj * 8]);
      }
#pragma unroll
      for (int nt = 0; nt < 4; ++nt) {
        int row = s0 + nt * 16 + lr;
        int jj = (j & 8) | ((j & 7) ^ (row & 7));
        bv[nt] =
            *reinterpret_cast<const bf16x8*>(&lb[ch & 1][row * 128 + jj * 8]);
      }
#pragma unroll
      for (int mt = 0; mt < 2; ++mt)
#pragma unroll
        for (int nt = 0; nt < 4; ++nt)
          acc[mt][nt] = mfma16(av[mt], bv[nt], acc[mt][nt]);
    }
    if (ch < 3) {
      __builtin_amdgcn_s_barrier();
      if (ch + 2 < 4) {
        stageB(ch + 2);
        asm volatile("s_waitcnt vmcnt(8)" ::: "memory");
      } else {
        asm volatile("s_waitcnt vmcnt(0)" ::: "memory");
      }
      __builtin_amdgcn_s_barrier();
    }
  }
#pragma unroll
  for (int mt = 0; mt < 2; ++mt) {
    int c = cb + c0 + mt * 16 + g * 4;
#pragma unroll
    for (int nt = 0; nt < 4; ++nt) {
      int s = sb + s0 + nt * 16 + lr;
#pragma unroll
      for (int r = 0; r < 4; ++r)
        OUT[((size_t)b * NC + c + r) * NS + s] = acc[mt][nt][r];
    }
  }
}

extern "C" void kernel_launch(void* const* d_in, const int* in_sizes, int n_in,
                              void* d_out, int out_size, void* d_ws,
                              size_t ws_size, hipStream_t stream) {
  const float* in1 = (const float*)d_in[0];
  const float* in2 = (const float*)d_in[1];
  const float* Wk1 = (const float*)d_in[2];
  const float* Wk2 = (const float*)d_in[3];
  const float* Wv2 = (const float*)d_in[4];
  const float* Wo = (const float*)d_in[5];
  float* out = (float*)d_out;

  bf16_t* w = (bf16_t*)d_ws;
  bf16_t* XT1 = w;
  bf16_t* XT2 = XT1 + (size_t)NB * NS * NC;
  bf16_t* K1 = XT2 + (size_t)NB * NS * NC;
  bf16_t* K2 = K1 + (size_t)NB * NHD * NS * ND;
  bf16_t* VT = K2 + (size_t)NB * NHD * NS * ND;
  bf16_t* AO = VT + (size_t)NB * NHD * NS * ND;
  bf16_t* Wk1b = AO + (size_t)NB * NS * NO;
  bf16_t* Wk2b = Wk1b + NO * NC;
  bf16_t* Wv2b = Wk2b + NO * NC;
  bf16_t* Wob = Wv2b + NO * NC;

  k_prep<<<dim3(32, 8, 18), dim3(32, 8), 0, stream>>>(
      in1, in2, Wk1, Wk2, Wv2, Wo, XT1, XT2, Wk1b, Wk2b, Wv2b, Wob);

  k_proj<<<768, 256, 0, stream>>>(Wk1b, Wk2b, Wv2b, XT1, XT2, K1, K2, VT);

  k_attn<<<512, 256, 0, stream>>>(K1, K2, VT, AO);

  k_oprojs<<<256, 256, 0, stream>>>(Wob, AO, out);
}

// Round 7
// 59.151 us; speedup vs baseline: 1.0041x; 1.0041x over previous
//
#include <hip/hip_runtime.h>
#include <stdint.h>

typedef __bf16 bf16_t;
typedef __attribute__((ext_vector_type(8))) __bf16 bf16x8;
typedef __attribute__((ext_vector_type(4))) __bf16 bf16x4;
typedef __attribute__((ext_vector_type(4))) float f32x4;

#define NB 8
#define NC 256
#define NS 1024
#define NHD 8
#define ND 64
#define NO 512

// 0.125 (1/sqrt(64)) * log2(e), folded into K1 so P = exp2(score)
#define QK_SCALE 0.18033688011112042f

__device__ __forceinline__ f32x4 mfma16(bf16x8 a, bf16x8 b, f32x4 c) {
  return __builtin_amdgcn_mfma_f32_16x16x32_bf16(a, b, c, 0, 0, 0);
}

// async global->LDS, 16B per lane; LDS dest = wave-uniform base + lane*16
__device__ __forceinline__ void gll16(const bf16_t* g, const bf16_t* l) {
  auto gp = (const __attribute__((address_space(1))) void*)(uintptr_t)g;
  auto lp = (__attribute__((address_space(3))) void*)(uint32_t)(uintptr_t)l;
  __builtin_amdgcn_global_load_lds(gp, lp, 16, 0, 0);
}

// ---------------- fused prep: transposes + weight converts ----------------
// z 0..7: in1 batch z -> XT1 ; z 8..15: in2 -> XT2 ; z 16,17: weights
__global__ __launch_bounds__(256) void k_prep(
    const float* __restrict__ in1, const float* __restrict__ in2,
    const float* __restrict__ w0, const float* __restrict__ w1,
    const float* __restrict__ w2, const float* __restrict__ w3,
    bf16_t* __restrict__ xt1, bf16_t* __restrict__ xt2,
    bf16_t* __restrict__ wb0, bf16_t* __restrict__ wb1,
    bf16_t* __restrict__ wb2, bf16_t* __restrict__ wb3) {
  int z = blockIdx.z;
  int tx = threadIdx.x, ty = threadIdx.y;
  if (z < 16) {
    __shared__ float tile[32][33];
    const float* x = (z < 8) ? in1 : in2;
    bf16_t* xt = (z < 8) ? xt1 : xt2;
    int b = z & 7;
    int s0 = blockIdx.x * 32, c0 = blockIdx.y * 32;
    const float* xb = x + (size_t)b * NC * NS;
#pragma unroll
    for (int i = 0; i < 4; ++i)
      tile[ty + 8 * i][tx] = xb[(size_t)(c0 + ty + 8 * i) * NS + s0 + tx];
    __syncthreads();
    bf16_t* xtb = xt + (size_t)b * NS * NC;
#pragma unroll
    for (int i = 0; i < 4; ++i)
      xtb[(size_t)(s0 + ty + 8 * i) * NC + c0 + tx] =
          (bf16_t)tile[tx][ty + 8 * i];
  } else {
    int f = ((blockIdx.y * 32 + blockIdx.x) * 256 + ty * 32 + tx) * 4;
    int mat = f >> 17, off = f & 131071;
    const float* s;
    bf16_t* d;
    if (z == 16) {
      s = mat ? w1 : w0; d = mat ? wb1 : wb0;
    } else {
      s = mat ? w3 : w2; d = mat ? wb3 : wb2;
    }
    float4 v = *reinterpret_cast<const float4*>(s + off);
    bf16x4 o;
    o[0] = (bf16_t)v.x; o[1] = (bf16_t)v.y;
    o[2] = (bf16_t)v.z; o[3] = (bf16_t)v.w;
    *reinterpret_cast<bf16x4*>(d + off) = o;
  }
}

// ---------------- fused projections (K1, K2, VT) ----------------
// grid 768: sel = id>>8 (0:K1 1:K2 2:VT); inner 256: b=id&7, o-blk, s-blk.
// BK=64 chunks, double-buffered global_load_lds, counted vmcnt(8).
// 128x128 tile, 4 waves x 64x64. XOR-swizzle granule(16B) ^= row&7.
__global__ __launch_bounds__(256) void k_proj(
    const bf16_t* __restrict__ Wk1b, const bf16_t* __restrict__ Wk2b,
    const bf16_t* __restrict__ Wv2b, const bf16_t* __restrict__ XT1,
    const bf16_t* __restrict__ XT2, bf16_t* __restrict__ K1,
    bf16_t* __restrict__ K2, bf16_t* __restrict__ VT) {
  __shared__ __align__(16) bf16_t lw[2][128 * 64];
  __shared__ __align__(16) bf16_t lx[2][128 * 64];
  int id = blockIdx.x;
  int sel = id >> 8;
  id &= 255;
  int b = id & 7;
  int ob = ((id >> 3) & 3) * 128;
  int sb = (id >> 5) * 128;
  int tid = threadIdx.x, wid = tid >> 6, lane = tid & 63;
  int lr = lane & 15, g = lane >> 4;
  const bf16_t* W = sel == 0 ? Wk1b : (sel == 1 ? Wk2b : Wv2b);
  const bf16_t* xt = (sel == 0 ? XT1 : XT2) + ((size_t)b * NS + sb) * NC;
  const bf16_t* wsrc = W + (size_t)ob * NC;

  int srow8 = lane >> 3, scol = lane & 7;
  auto stage = [&](int c, int bs) {
#pragma unroll
    for (int i = 0; i < 4; ++i) {
      int row = i * 32 + wid * 8 + srow8;
      int cs = scol ^ (row & 7);
      gll16(wsrc + (size_t)row * NC + c * 64 + cs * 8,
            &lw[bs][(i * 32 + wid * 8) * 64]);
      gll16(xt + (size_t)row * NC + c * 64 + cs * 8,
            &lx[bs][(i * 32 + wid * 8) * 64]);
    }
  };
  stage(0, 0);

  int m0 = (wid >> 1) * 64, n0 = (wid & 1) * 64;
  f32x4 acc[4][4];
#pragma unroll
  for (int mt = 0; mt < 4; ++mt)
#pragma unroll
    for (int nt = 0; nt < 4; ++nt) acc[mt][nt] = (f32x4){0.f, 0.f, 0.f, 0.f};

  for (int c = 0; c < 4; ++c) {
    int cb2 = c & 1;
    if (c < 3) {
      stage(c + 1, cb2 ^ 1);
      asm volatile("s_waitcnt vmcnt(8)" ::: "memory");
    } else {
      asm volatile("s_waitcnt vmcnt(0)" ::: "memory");
    }
    __builtin_amdgcn_s_barrier();
    const bf16_t* aw = sel < 2 ? lw[cb2] : lx[cb2];  // A rows (m)
    const bf16_t* bx = sel < 2 ? lx[cb2] : lw[cb2];  // B rows (n)
#pragma unroll
    for (int kk = 0; kk < 2; ++kk) {
      int j = kk * 4 + g;
      bf16x8 av[4], bv[4];
#pragma unroll
      for (int mt = 0; mt < 4; ++mt) {
        int row = m0 + mt * 16 + lr;
        av[mt] =
            *reinterpret_cast<const bf16x8*>(aw + row * 64 + (j ^ (row & 7)) * 8);
      }
#pragma unroll
      for (int nt = 0; nt < 4; ++nt) {
        int row = n0 + nt * 16 + lr;
        bv[nt] =
            *reinterpret_cast<const bf16x8*>(bx + row * 64 + (j ^ (row & 7)) * 8);
      }
#pragma unroll
      for (int mt = 0; mt < 4; ++mt)
#pragma unroll
        for (int nt = 0; nt < 4; ++nt)
          acc[mt][nt] = mfma16(av[mt], bv[nt], acc[mt][nt]);
    }
    __builtin_amdgcn_s_barrier();
  }

  if (sel < 2) {
    // D rows = o, cols = s; store K[b][h][s][d], d contiguous x4
    float scale = sel == 0 ? QK_SCALE : 1.0f;
    bf16_t* K = sel == 0 ? K1 : K2;
#pragma unroll
    for (int mt = 0; mt < 4; ++mt) {
      int oRow = ob + m0 + mt * 16 + g * 4;
      int hh = oRow >> 6, d0 = oRow & 63;
#pragma unroll
      for (int nt = 0; nt < 4; ++nt) {
        int s = sb + n0 + nt * 16 + lr;
        bf16x4 pk;
        pk[0] = (bf16_t)(acc[mt][nt][0] * scale);
        pk[1] = (bf16_t)(acc[mt][nt][1] * scale);
        pk[2] = (bf16_t)(acc[mt][nt][2] * scale);
        pk[3] = (bf16_t)(acc[mt][nt][3] * scale);
        *reinterpret_cast<bf16x4*>(
            K + (((size_t)b * NHD + hh) * NS + s) * ND + d0) = pk;
      }
    }
  } else {
    // D rows = s, cols = o; store VT[b][h][d][s], s contiguous x4
#pragma unroll
    for (int mt = 0; mt < 4; ++mt) {
      int sRow = sb + m0 + mt * 16 + g * 4;
#pragma unroll
      for (int nt = 0; nt < 4; ++nt) {
        int o = ob + n0 + nt * 16 + lr;
        int hh = o >> 6, d = o & 63;
        bf16x4 pk;
        pk[0] = (bf16_t)acc[mt][nt][0];
        pk[1] = (bf16_t)acc[mt][nt][1];
        pk[2] = (bf16_t)acc[mt][nt][2];
        pk[3] = (bf16_t)acc[mt][nt][3];
        *reinterpret_cast<bf16x4*>(
            VT + (((size_t)b * NHD + hh) * ND + d) * NS + sRow) = pk;
      }
    }
  }
}

// ---------------- fused flash attention (LDS K/V, swapped QK^T) ----------------
// QK^T computed as mfma(K2,K1): lane gets P^T[k=g*4+r][q=lr] -> 4 consecutive
// k per lane -> packed ds_write_b64 into P_lds[q][k] (XOR-swizzled by q&14),
// read back contiguous b128 as PV A-frag. Row-sum l is column-indexed (q=lr),
// reduced across g-groups + redistributed by __shfl in the epilogue.
__global__ __launch_bounds__(256) void k_attn(const bf16_t* __restrict__ K1,
                                              const bf16_t* __restrict__ K2,
                                              const bf16_t* __restrict__ VT,
                                              bf16_t* __restrict__ AO) {
  __shared__ __align__(16) bf16_t kbuf[2][64 * 64];
  __shared__ __align__(16) bf16_t vbuf[2][64 * 64];
  __shared__ __align__(16) bf16_t plds[4][32 * 64];

  int id = blockIdx.x;
  int bh = (id & 7) * 8 + ((id >> 3) & 7);  // id&7 = batch -> per-XCD L2
  int qb = (id >> 6) * 128;
  int tid = threadIdx.x, wid = tid >> 6, lane = tid & 63;
  int lr = lane & 15, g = lane >> 4;
  const bf16_t* k1 = K1 + (size_t)bh * NS * ND;
  const bf16_t* k2 = K2 + (size_t)bh * NS * ND;
  const bf16_t* vt = VT + (size_t)bh * ND * NS;
  int q0 = qb + wid * 32;

  bf16x8 aq[2][2];
#pragma unroll
  for (int qg = 0; qg < 2; ++qg)
#pragma unroll
    for (int kh = 0; kh < 2; ++kh)
      aq[qg][kh] = *reinterpret_cast<const bf16x8*>(
          k1 + (size_t)(q0 + qg * 16 + lr) * ND + kh * 32 + g * 8);

  f32x4 acc[2][4];
  float l[2] = {0.f, 0.f};
#pragma unroll
  for (int qg = 0; qg < 2; ++qg)
#pragma unroll
    for (int dt = 0; dt < 4; ++dt) acc[qg][dt] = (f32x4){0.f, 0.f, 0.f, 0.f};

  int srow = lane >> 3;
  int sx = ((lane & 7) ^ srow) * 8;
  auto stage = [&](int kc, int bs) {
#pragma unroll
    for (int i2 = 0; i2 < 2; ++i2) {
      int row = (wid * 2 + i2) * 8 + srow;
      gll16(k2 + (size_t)(kc + row) * ND + sx, &kbuf[bs][(wid * 2 + i2) * 512]);
      gll16(vt + (size_t)row * NS + kc + sx, &vbuf[bs][(wid * 2 + i2) * 512]);
    }
  };
  stage(0, 0);

  bf16_t* pw = plds[wid];
  int keyr = lr & 14;  // P swizzle key (preserves 16B granule pairs)
  for (int it = 0; it < 16; ++it) {
    int cur = it & 1;
    if (it < 15) {
      stage((it + 1) * 64, cur ^ 1);
      asm volatile("s_waitcnt vmcnt(4)" ::: "memory");
    } else {
      asm volatile("s_waitcnt vmcnt(0)" ::: "memory");
    }
    __builtin_amdgcn_s_barrier();
    const bf16_t* kb = kbuf[cur];
    const bf16_t* vb = vbuf[cur];

    // scores^T = K2 . K1^T : rows = k2-chunk (4 tiles), cols = q (2 tiles)
    f32x4 sct[2][4];
#pragma unroll
    for (int qg = 0; qg < 2; ++qg)
#pragma unroll
      for (int t = 0; t < 4; ++t) sct[qg][t] = (f32x4){0.f, 0.f, 0.f, 0.f};
#pragma unroll
    for (int t = 0; t < 4; ++t) {
      const bf16_t* kr = kb + (t * 16 + lr) * 64;
      bf16x8 b0 = *reinterpret_cast<const bf16x8*>(kr + ((g ^ (lr & 7)) << 3));
      bf16x8 b1 =
          *reinterpret_cast<const bf16x8*>(kr + (((4 + g) ^ (lr & 7)) << 3));
#pragma unroll
      for (int qg = 0; qg < 2; ++qg) {
        sct[qg][t] = mfma16(b0, aq[qg][0], sct[qg][t]);
        sct[qg][t] = mfma16(b1, aq[qg][1], sct[qg][t]);
      }
    }
    // P = exp2; pack 4 consecutive k -> one b64 write per (qg,t)
#pragma unroll
    for (int qg = 0; qg < 2; ++qg)
#pragma unroll
      for (int t = 0; t < 4; ++t) {
        float p0 = __builtin_amdgcn_exp2f(sct[qg][t][0]);
        float p1 = __builtin_amdgcn_exp2f(sct[qg][t][1]);
        float p2 = __builtin_amdgcn_exp2f(sct[qg][t][2]);
        float p3 = __builtin_amdgcn_exp2f(sct[qg][t][3]);
        l[qg] += (p0 + p1) + (p2 + p3);
        bf16x4 pk;
        pk[0] = (bf16_t)p0; pk[1] = (bf16_t)p1;
        pk[2] = (bf16_t)p2; pk[3] = (bf16_t)p3;
        int c8 = (t * 4 + g) ^ keyr;
        *reinterpret_cast<bf16x4*>(pw + (qg * 16 + lr) * 64 + c8 * 4) = pk;
      }
    // PV: A = P (contiguous b128 from swizzled LDS), B = VT chunk
#pragma unroll
    for (int kc2 = 0; kc2 < 2; ++kc2) {
      bf16x8 pA[2];
#pragma unroll
      for (int qg = 0; qg < 2; ++qg)
        pA[qg] = *reinterpret_cast<const bf16x8*>(
            pw + (qg * 16 + lr) * 64 + ((kc2 * 8 + g * 2) ^ keyr) * 4);
#pragma unroll
      for (int dt = 0; dt < 4; ++dt) {
        const bf16_t* vr = vb + (dt * 16 + lr) * 64;
        bf16x8 vB = *reinterpret_cast<const bf16x8*>(
            vr + (((kc2 * 4 + g) ^ (lr & 7)) << 3));
#pragma unroll
        for (int qg = 0; qg < 2; ++qg)
          acc[qg][dt] = mfma16(pA[qg], vB, acc[qg][dt]);
      }
    }
    __builtin_amdgcn_s_barrier();
  }

  // epilogue: reduce l (per q-column) across g-groups, redistribute, store
  int b = bh >> 3, h = bh & 7;
  float L[2];
#pragma unroll
  for (int qg = 0; qg < 2; ++qg) {
    float rs = l[qg];
    rs += __shfl_xor(rs, 16);
    rs += __shfl_xor(rs, 32);
    L[qg] = rs;
  }
#pragma unroll
  for (int qg = 0; qg < 2; ++qg) {
    float linv[4];
#pragma unroll
    for (int r = 0; r < 4; ++r)
      linv[r] = 1.0f / __shfl(L[qg], g * 4 + r);
#pragma unroll
    for (int dt = 0; dt < 4; ++dt) {
      int d = dt * 16 + lr;
#pragma unroll
      for (int r = 0; r < 4; ++r) {
        int s = q0 + qg * 16 + g * 4 + r;
        AO[((size_t)b * NS + s) * NO + h * ND + d] =
            (bf16_t)(acc[qg][dt][r] * linv[r]);
      }
    }
  }
}

// ---------------- output projection, LDS-staged ----------------
__global__ __launch_bounds__(256) void k_oprojs(const bf16_t* __restrict__ Wob,
                                                const bf16_t* __restrict__ AO,
                                                float* __restrict__ OUT) {
  __shared__ __align__(16) bf16_t la[64 * 512];
  __shared__ __align__(16) bf16_t lb[2][128 * 128];
  int id = blockIdx.x;
  int b = id & 7;
  int cb = ((id >> 3) & 3) * 64;
  int sb = (id >> 5) * 128;
  int tid = threadIdx.x, wid = tid >> 6, lane = tid & 63;
  int lr = lane & 15, g = lane >> 4;
  const bf16_t* asrc = Wob + (size_t)cb * NO;
  const bf16_t* bsrc = AO + ((size_t)b * NS + sb) * NO;

  {
    int c = lane;
#pragma unroll
    for (int it = 0; it < 16; ++it) {
      int row = it * 4 + wid;
      int cs = (c & 56) | ((c & 7) ^ (row & 7));
      gll16(asrc + (size_t)row * NO + cs * 8, &la[row * 512]);
    }
  }
  int sr = tid >> 4, sc = tid & 15;
  auto stageB = [&](int ch) {
#pragma unroll
    for (int it = 0; it < 8; ++it) {
      int row = it * 16 + sr;
      int cs = (sc & 8) | ((sc & 7) ^ (row & 7));
      gll16(bsrc + (size_t)row * NO + ch * 128 + cs * 8,
            &lb[ch & 1][(it * 16 + wid * 4) * 128]);
    }
  };
  stageB(0);
  stageB(1);
  asm volatile("s_waitcnt vmcnt(8)" ::: "memory");
  __builtin_amdgcn_s_barrier();

  int c0 = (wid >> 1) * 32, s0 = (wid & 1) * 64;
  f32x4 acc[2][4];
#pragma unroll
  for (int mt = 0; mt < 2; ++mt)
#pragma unroll
    for (int nt = 0; nt < 4; ++nt) acc[mt][nt] = (f32x4){0.f, 0.f, 0.f, 0.f};

#pragma unroll
  for (int ch = 0; ch < 4; ++ch) {
#pragma unroll
    for (int kk = 0; kk < 4; ++kk) {
      int j = kk * 4 + g;
      bf16x8 av[2], bv[4];
#pragma unroll
      for (int mt = 0; mt < 2; ++mt) {
        int row = c0 + mt * 16 + lr;
        int jh = ch * 16 + j;
        int jj = (jh & 56) | ((jh & 7) ^ (row & 7));
        av[mt] = *reinterpret_cast<const bf16x8*>(&la[row * 512 + jj * 8]);
      }
#pragma unroll
      for (int nt = 0; nt < 4; ++nt) {
        int row = s0 + nt * 16 + lr;
        int jj = (j & 8) | ((j & 7) ^ (row & 7));
        bv[nt] =
            *reinterpret_cast<const bf16x8*>(&lb[ch & 1][row * 128 + jj * 8]);
      }
#pragma unroll
      for (int mt = 0; mt < 2; ++mt)
#pragma unroll
        for (int nt = 0; nt < 4; ++nt)
          acc[mt][nt] = mfma16(av[mt], bv[nt], acc[mt][nt]);
    }
    if (ch < 3) {
      __builtin_amdgcn_s_barrier();
      if (ch + 2 < 4) {
        stageB(ch + 2);
        asm volatile("s_waitcnt vmcnt(8)" ::: "memory");
      } else {
        asm volatile("s_waitcnt vmcnt(0)" ::: "memory");
      }
      __builtin_amdgcn_s_barrier();
    }
  }
#pragma unroll
  for (int mt = 0; mt < 2; ++mt) {
    int c = cb + c0 + mt * 16 + g * 4;
#pragma unroll
    for (int nt = 0; nt < 4; ++nt) {
      int s = sb + s0 + nt * 16 + lr;
#pragma unroll
      for (int r = 0; r < 4; ++r)
        OUT[((size_t)b * NC + c + r) * NS + s] = acc[mt][nt][r];
    }
  }
}

extern "C" void kernel_launch(void* const* d_in, const int* in_sizes, int n_in,
                              void* d_out, int out_size, void* d_ws,
                              size_t ws_size, hipStream_t stream) {
  const float* in1 = (const float*)d_in[0];
  const float* in2 = (const float*)d_in[1];
  const float* Wk1 = (const float*)d_in[2];
  const float* Wk2 = (const float*)d_in[3];
  const float* Wv2 = (const float*)d_in[4];
  const float* Wo = (const float*)d_in[5];
  float* out = (float*)d_out;

  bf16_t* w = (bf16_t*)d_ws;
  bf16_t* XT1 = w;
  bf16_t* XT2 = XT1 + (size_t)NB * NS * NC;
  bf16_t* K1 = XT2 + (size_t)NB * NS * NC;
  bf16_t* K2 = K1 + (size_t)NB * NHD * NS * ND;
  bf16_t* VT = K2 + (size_t)NB * NHD * NS * ND;
  bf16_t* AO = VT + (size_t)NB * NHD * NS * ND;
  bf16_t* Wk1b = AO + (size_t)NB * NS * NO;
  bf16_t* Wk2b = Wk1b + NO * NC;
  bf16_t* Wv2b = Wk2b + NO * NC;
  bf16_t* Wob = Wv2b + NO * NC;

  k_prep<<<dim3(32, 8, 18), dim3(32, 8), 0, stream>>>(
      in1, in2, Wk1, Wk2, Wv2, Wo, XT1, XT2, Wk1b, Wk2b, Wv2b, Wob);

  k_proj<<<768, 256, 0, stream>>>(Wk1b, Wk2b, Wv2b, XT1, XT2, K1, K2, VT);

  k_attn<<<512, 256, 0, stream>>>(K1, K2, VT, AO);

  k_oprojs<<<256, 256, 0, stream>>>(Wob, AO, out);
}